// Round 1
// baseline (818.453 us; speedup 1.0000x reference)
//
#include <hip/hip_runtime.h>

#define NATOMS 64
#define VDIM 100
#define FDIM 128
#define HDIM 256
#define NCONV 4

// XOR swizzle on float index: permutes 16B groups within a row to break
// stride-128 (same-bank) conflicts for per-row ds_read_b128.
__device__ __forceinline__ int swz(int row, int col) {
  return row * FDIM + (col ^ ((row & 7) << 2));
}

__device__ __forceinline__ float lrelu(float x) {
  return x >= 0.0f ? x : 0.01f * x;
}

__launch_bounds__(256, 1)
__global__ void gcn_fused(
    const float* __restrict__ node, const float* __restrict__ adj,
    const float* __restrict__ W_init, const float* __restrict__ b_init,
    const float* __restrict__ W_conv, const float* __restrict__ b_conv,
    const float* __restrict__ W_fc0, const float* __restrict__ b_fc0,
    const float* __restrict__ W_fc1, const float* __restrict__ b_fc1,
    const float* __restrict__ W_out, const float* __restrict__ b_out,
    float* __restrict__ out) {
  __shared__ float bufA[NATOMS * FDIM];  // 32 KB: x
  __shared__ float bufB[NATOMS * FDIM];  // 32 KB: node / agg / head scratch

  const int b = blockIdx.x;
  const int t = threadIdx.x;
  const int tn = t >> 4;   // 0..15
  const int tf = t & 15;   // 0..15
  const int f0 = tf * 8;
  int rows[4];
#pragma unroll
  for (int j = 0; j < 4; ++j) rows[j] = tn + 16 * j;

  // ---- Phase 0: stage adj, build per-row bitmask + 1/deg ----
  {
    const float4* a4 = (const float4*)(adj + (size_t)b * NATOMS * NATOMS);
    float4* d4 = (float4*)bufA;
#pragma unroll
    for (int i = 0; i < 4; ++i) d4[t + 256 * i] = a4[t + 256 * i];
  }
  __syncthreads();
  unsigned* mlo_s = (unsigned*)bufB;
  unsigned* mhi_s = ((unsigned*)bufB) + 64;
  float* rdg_s = bufB + 128;
  if (t < NATOMS) {
    unsigned lo = 0, hi = 0;
    int deg = 0;
    // rotate start column by t to avoid 64-deep same-bank serialization
    for (int c = 0; c < NATOMS; ++c) {
      int cc = (c + t) & 63;
      if (bufA[t * 64 + cc] != 0.0f) {
        deg++;
        if (cc < 32) lo |= (1u << cc); else hi |= (1u << (cc - 32));
      }
    }
    mlo_s[t] = lo; mhi_s[t] = hi;
    rdg_s[t] = 1.0f / (float)(deg < 1 ? 1 : deg);
  }
  __syncthreads();
  unsigned mlo[4], mhi[4];
  float rdg[4];
#pragma unroll
  for (int j = 0; j < 4; ++j) {
    mlo[j] = mlo_s[rows[j]];
    mhi[j] = mhi_s[rows[j]];
    rdg[j] = rdg_s[rows[j]];
  }
  __syncthreads();

  // ---- Phase 1: stage node (64x100, stride 100) into bufB ----
  {
    const float4* n4 = (const float4*)(node + (size_t)b * NATOMS * VDIM);
    float4* d4 = (float4*)bufB;
    for (int i = t; i < NATOMS * VDIM / 4; i += 256) d4[i] = n4[i];
  }
  __syncthreads();

  // ---- Phase 2: x = lrelu(node @ W_init + b_init) -> bufA (swizzled) ----
  {
    float acc[4][8];
#pragma unroll
    for (int j = 0; j < 4; ++j)
#pragma unroll
      for (int i = 0; i < 8; ++i) acc[j][i] = 0.0f;
    for (int v = 0; v < VDIM; v += 4) {
      float av[4][4];
#pragma unroll
      for (int j = 0; j < 4; ++j) {
        float4 tmp = *(const float4*)&bufB[rows[j] * VDIM + v];
        av[j][0] = tmp.x; av[j][1] = tmp.y; av[j][2] = tmp.z; av[j][3] = tmp.w;
      }
#pragma unroll
      for (int c = 0; c < 4; ++c) {
        float4 w0 = *(const float4*)&W_init[(v + c) * FDIM + f0];
        float4 w1 = *(const float4*)&W_init[(v + c) * FDIM + f0 + 4];
        float w[8] = {w0.x, w0.y, w0.z, w0.w, w1.x, w1.y, w1.z, w1.w};
#pragma unroll
        for (int j = 0; j < 4; ++j)
#pragma unroll
          for (int i = 0; i < 8; ++i) acc[j][i] += av[j][c] * w[i];
      }
    }
    float4 bi0 = *(const float4*)&b_init[f0];
    float4 bi1 = *(const float4*)&b_init[f0 + 4];
    float bi[8] = {bi0.x, bi0.y, bi0.z, bi0.w, bi1.x, bi1.y, bi1.z, bi1.w};
#pragma unroll
    for (int j = 0; j < 4; ++j) {
      float4 o0, o1;
      o0.x = lrelu(acc[j][0] + bi[0]);
      o0.y = lrelu(acc[j][1] + bi[1]);
      o0.z = lrelu(acc[j][2] + bi[2]);
      o0.w = lrelu(acc[j][3] + bi[3]);
      o1.x = lrelu(acc[j][4] + bi[4]);
      o1.y = lrelu(acc[j][5] + bi[5]);
      o1.z = lrelu(acc[j][6] + bi[6]);
      o1.w = lrelu(acc[j][7] + bi[7]);
      *(float4*)&bufA[swz(rows[j], f0)] = o0;
      *(float4*)&bufA[swz(rows[j], f0 + 4)] = o1;
    }
  }
  __syncthreads();

  // ---- Conv layers ----
  for (int layer = 0; layer < NCONV; ++layer) {
    const float* Wl = W_conv + layer * FDIM * FDIM;
    const float* bl = b_conv + layer * FDIM;

    // Phase A: agg = rdeg * (mask-select sum over x rows)  (bufA -> bufB)
    {
      float acc[4][8];
#pragma unroll
      for (int j = 0; j < 4; ++j)
#pragma unroll
        for (int i = 0; i < 8; ++i) acc[j][i] = 0.0f;
#pragma unroll 8
      for (int k = 0; k < 32; ++k) {
        float4 x0 = *(const float4*)&bufA[swz(k, f0)];
        float4 x1 = *(const float4*)&bufA[swz(k, f0 + 4)];
        float xv[8] = {x0.x, x0.y, x0.z, x0.w, x1.x, x1.y, x1.z, x1.w};
#pragma unroll
        for (int j = 0; j < 4; ++j) {
          float s = (float)((mlo[j] >> k) & 1u);
#pragma unroll
          for (int i = 0; i < 8; ++i) acc[j][i] += s * xv[i];
        }
      }
#pragma unroll 8
      for (int k = 0; k < 32; ++k) {
        float4 x0 = *(const float4*)&bufA[swz(k + 32, f0)];
        float4 x1 = *(const float4*)&bufA[swz(k + 32, f0 + 4)];
        float xv[8] = {x0.x, x0.y, x0.z, x0.w, x1.x, x1.y, x1.z, x1.w};
#pragma unroll
        for (int j = 0; j < 4; ++j) {
          float s = (float)((mhi[j] >> k) & 1u);
#pragma unroll
          for (int i = 0; i < 8; ++i) acc[j][i] += s * xv[i];
        }
      }
#pragma unroll
      for (int j = 0; j < 4; ++j) {
        float4 o0, o1;
        o0.x = acc[j][0] * rdg[j]; o0.y = acc[j][1] * rdg[j];
        o0.z = acc[j][2] * rdg[j]; o0.w = acc[j][3] * rdg[j];
        o1.x = acc[j][4] * rdg[j]; o1.y = acc[j][5] * rdg[j];
        o1.z = acc[j][6] * rdg[j]; o1.w = acc[j][7] * rdg[j];
        *(float4*)&bufB[swz(rows[j], f0)] = o0;
        *(float4*)&bufB[swz(rows[j], f0 + 4)] = o1;
      }
    }
    __syncthreads();

    // Phase B: x = lrelu(agg @ Wl + bl)  (bufB -> bufA)
    {
      float acc[4][8];
#pragma unroll
      for (int j = 0; j < 4; ++j)
#pragma unroll
        for (int i = 0; i < 8; ++i) acc[j][i] = 0.0f;
#pragma unroll 2
      for (int k = 0; k < FDIM; k += 4) {
        float av[4][4];
#pragma unroll
        for (int j = 0; j < 4; ++j) {
          float4 tmp = *(const float4*)&bufB[swz(rows[j], k)];
          av[j][0] = tmp.x; av[j][1] = tmp.y; av[j][2] = tmp.z; av[j][3] = tmp.w;
        }
#pragma unroll
        for (int c = 0; c < 4; ++c) {
          float4 w0 = *(const float4*)&Wl[(k + c) * FDIM + f0];
          float4 w1 = *(const float4*)&Wl[(k + c) * FDIM + f0 + 4];
          float w[8] = {w0.x, w0.y, w0.z, w0.w, w1.x, w1.y, w1.z, w1.w};
#pragma unroll
          for (int j = 0; j < 4; ++j)
#pragma unroll
            for (int i = 0; i < 8; ++i) acc[j][i] += av[j][c] * w[i];
        }
      }
      float4 bi0 = *(const float4*)&bl[f0];
      float4 bi1 = *(const float4*)&bl[f0 + 4];
      float bi[8] = {bi0.x, bi0.y, bi0.z, bi0.w, bi1.x, bi1.y, bi1.z, bi1.w};
#pragma unroll
      for (int j = 0; j < 4; ++j) {
        float4 o0, o1;
        o0.x = lrelu(acc[j][0] + bi[0]);
        o0.y = lrelu(acc[j][1] + bi[1]);
        o0.z = lrelu(acc[j][2] + bi[2]);
        o0.w = lrelu(acc[j][3] + bi[3]);
        o1.x = lrelu(acc[j][4] + bi[4]);
        o1.y = lrelu(acc[j][5] + bi[5]);
        o1.z = lrelu(acc[j][6] + bi[6]);
        o1.w = lrelu(acc[j][7] + bi[7]);
        *(float4*)&bufA[swz(rows[j], f0)] = o0;
        *(float4*)&bufA[swz(rows[j], f0 + 4)] = o1;
      }
    }
    __syncthreads();
  }

  // ---- Mean pool over atoms: g[f] -> bufB[0..127] ----
  if (t < FDIM) {
    float s = 0.0f;
#pragma unroll 8
    for (int n = 0; n < NATOMS; ++n) s += bufA[swz(n, t)];
    bufB[t] = s * (1.0f / 64.0f);
  }
  __syncthreads();

  // ---- FC head ----
  float h0 = b_fc0[t];
  for (int k = 0; k < FDIM; k += 4) {
    float4 g4 = *(const float4*)&bufB[k];
    h0 += g4.x * W_fc0[(k + 0) * HDIM + t] + g4.y * W_fc0[(k + 1) * HDIM + t] +
          g4.z * W_fc0[(k + 2) * HDIM + t] + g4.w * W_fc0[(k + 3) * HDIM + t];
  }
  h0 = lrelu(h0);
  bufB[FDIM + t] = h0;
  __syncthreads();

  float h1 = b_fc1[t];
  for (int k = 0; k < HDIM; k += 4) {
    float4 g4 = *(const float4*)&bufB[FDIM + k];
    h1 += g4.x * W_fc1[(k + 0) * HDIM + t] + g4.y * W_fc1[(k + 1) * HDIM + t] +
          g4.z * W_fc1[(k + 2) * HDIM + t] + g4.w * W_fc1[(k + 3) * HDIM + t];
  }
  h1 = lrelu(h1);
  float p = h1 * W_out[t];

  float* red = bufB + 512;
  red[t] = p;
  __syncthreads();
  for (int s = 128; s > 0; s >>= 1) {
    if (t < s) red[t] += red[t + s];
    __syncthreads();
  }
  if (t == 0) out[b] = red[0] + b_out[0];
}

extern "C" void kernel_launch(void* const* d_in, const int* in_sizes, int n_in,
                              void* d_out, int out_size, void* d_ws, size_t ws_size,
                              hipStream_t stream) {
  (void)in_sizes; (void)n_in; (void)d_ws; (void)ws_size; (void)out_size;
  const float* node   = (const float*)d_in[0];
  const float* adj    = (const float*)d_in[1];
  const float* W_init = (const float*)d_in[2];
  const float* b_init = (const float*)d_in[3];
  const float* W_conv = (const float*)d_in[4];
  const float* b_conv = (const float*)d_in[5];
  const float* W_fc0  = (const float*)d_in[6];
  const float* b_fc0  = (const float*)d_in[7];
  const float* W_fc1  = (const float*)d_in[8];
  const float* b_fc1  = (const float*)d_in[9];
  const float* W_out  = (const float*)d_in[10];
  const float* b_out  = (const float*)d_in[11];
  float* out = (float*)d_out;

  gcn_fused<<<4096, 256, 0, stream>>>(node, adj, W_init, b_init, W_conv, b_conv,
                                      W_fc0, b_fc0, W_fc1, b_fc1, W_out, b_out,
                                      out);
}

// Round 2
// 189.651 us; speedup vs baseline: 4.3156x; 4.3156x over previous
//
#include <hip/hip_runtime.h>

#define NATOMS 64
#define VDIM 100
#define FDIM 128
#define HDIM 256
#define NCONV 4

typedef __bf16 bf16x8 __attribute__((ext_vector_type(8)));
typedef __bf16 bf16x4 __attribute__((ext_vector_type(4)));
typedef float f32x4 __attribute__((ext_vector_type(4)));

__device__ __forceinline__ float lrelu(float x) {
  return x >= 0.0f ? x : 0.01f * x;
}

// ---------------- kernel 0: transpose weights to bf16 [n][k] ----------------
// WtI: [128 n][128 k] (k >= 100 zero-padded), WtC: [4][128 n][128 k]
__global__ void prep_weights(const float* __restrict__ Wi,
                             const float* __restrict__ Wc,
                             __bf16* __restrict__ WtI,
                             __bf16* __restrict__ WtC) {
  int idx = blockIdx.x * 256 + threadIdx.x;
  if (idx < FDIM * FDIM) {
    int n = idx >> 7, k = idx & 127;
    WtI[idx] = (__bf16)(k < VDIM ? Wi[k * FDIM + n] : 0.0f);
  } else if (idx < FDIM * FDIM * (1 + NCONV)) {
    int idx2 = idx - FDIM * FDIM;
    int l = idx2 >> 14, r = idx2 & 16383;
    int n = r >> 7, k = r & 127;
    WtC[idx2] = (__bf16)Wc[l * FDIM * FDIM + k * FDIM + n];
  }
}

// ---------------- kernel 1: fused GCN per molecule (MFMA) ----------------
__launch_bounds__(256, 2)
__global__ void gcn_mfma(const float* __restrict__ node,
                         const float* __restrict__ adj,
                         const __bf16* __restrict__ WtI,
                         const __bf16* __restrict__ WtC,
                         const float* __restrict__ b_init,
                         const float* __restrict__ b_conv,
                         float* __restrict__ g_out) {
  // xT[feat][atom] (swizzled), row/agg [atom][k] (swizzled), adjS[n][k] (swizzled)
  __shared__ __align__(16) __bf16 sXT[FDIM * NATOMS];   // 16 KB
  __shared__ __align__(16) __bf16 sRow[NATOMS * FDIM];  // 16 KB
  __shared__ __align__(16) __bf16 sAdj[NATOMS * NATOMS];// 8 KB
  __shared__ float sDegP[NATOMS * 8];                   // 2 KB
  __shared__ float sRdg[NATOMS];

  const int b = blockIdx.x;
  const int t = threadIdx.x;
  const int lane = t & 63;
  const int w = t >> 6;      // wave 0..3
  const int lr = lane & 15;  // fragment row/col within tile
  const int k0 = (lane >> 4) * 8;
  const int lg4 = (lane >> 4) * 4;

  // ---- stage adjacency (bf16, exact 0/1) + degree partials ----
  {
    const float* adjB = adj + (size_t)b * NATOMS * NATOMS;
    for (int u = t; u < 512; u += 256) {
      int n = u >> 3, gi = u & 7;
      float4 a0 = *(const float4*)&adjB[n * 64 + gi * 8];
      float4 a1 = *(const float4*)&adjB[n * 64 + gi * 8 + 4];
      bf16x8 v;
      v[0] = (__bf16)a0.x; v[1] = (__bf16)a0.y; v[2] = (__bf16)a0.z; v[3] = (__bf16)a0.w;
      v[4] = (__bf16)a1.x; v[5] = (__bf16)a1.y; v[6] = (__bf16)a1.z; v[7] = (__bf16)a1.w;
      *(bf16x8*)&sAdj[n * 64 + ((gi * 8) ^ ((n & 7) << 3))] = v;
      sDegP[n * 8 + gi] = a0.x + a0.y + a0.z + a0.w + a1.x + a1.y + a1.z + a1.w;
    }
  }
  // ---- stage node -> sRow [atom][128] bf16, zero-pad k=100..127 ----
  {
    const float* nodeB = node + (size_t)b * NATOMS * VDIM;
    for (int u = t; u < 1024; u += 256) {
      int n = u >> 4, gi = u & 15;
      int kk = gi * 8;
      bf16x8 v;
      if (kk + 8 <= VDIM) {
        float4 a0 = *(const float4*)&nodeB[n * VDIM + kk];
        float4 a1 = *(const float4*)&nodeB[n * VDIM + kk + 4];
        v[0] = (__bf16)a0.x; v[1] = (__bf16)a0.y; v[2] = (__bf16)a0.z; v[3] = (__bf16)a0.w;
        v[4] = (__bf16)a1.x; v[5] = (__bf16)a1.y; v[6] = (__bf16)a1.z; v[7] = (__bf16)a1.w;
      } else {
#pragma unroll
        for (int i = 0; i < 8; ++i) {
          float x = (kk + i < VDIM) ? nodeB[n * VDIM + kk + i] : 0.0f;
          v[i] = (__bf16)x;
        }
      }
      *(bf16x8*)&sRow[n * 128 + (kk ^ ((n & 7) << 3))] = v;
    }
  }
  __syncthreads();
  if (t < NATOMS) {
    float s = 0.0f;
#pragma unroll
    for (int g = 0; g < 8; ++g) s += sDegP[t * 8 + g];
    sRdg[t] = 1.0f / fmaxf(s, 1.0f);
  }
  // (sRdg first read after the barrier that follows the init matmul)

  // ---- conv-type matmul: out = lrelu(sRow @ Wt^T-layout + bias) -> sXT ----
  auto conv_mm = [&](const __bf16* __restrict__ Wt, const float* __restrict__ bias) {
    f32x4 acc[2][4];
#pragma unroll
    for (int ni = 0; ni < 2; ++ni)
#pragma unroll
      for (int mi = 0; mi < 4; ++mi) acc[ni][mi] = {0.f, 0.f, 0.f, 0.f};
#pragma unroll
    for (int ks = 0; ks < 4; ++ks) {
      bf16x8 bfrag[2], afrag[4];
#pragma unroll
      for (int ni = 0; ni < 2; ++ni) {
        int n = (2 * w + ni) * 16 + lr;
        bfrag[ni] = *(const bf16x8*)&Wt[n * 128 + ks * 32 + k0];
      }
#pragma unroll
      for (int mi = 0; mi < 4; ++mi) {
        int m = mi * 16 + lr;
        afrag[mi] = *(const bf16x8*)&sRow[m * 128 + ((ks * 32 + k0) ^ ((m & 7) << 3))];
      }
#pragma unroll
      for (int ni = 0; ni < 2; ++ni)
#pragma unroll
        for (int mi = 0; mi < 4; ++mi)
          acc[ni][mi] = __builtin_amdgcn_mfma_f32_16x16x32_bf16(
              afrag[mi], bfrag[ni], acc[ni][mi], 0, 0, 0);
    }
#pragma unroll
    for (int ni = 0; ni < 2; ++ni) {
      int n = (2 * w + ni) * 16 + lr;  // feature column
      float bv = bias[n];
#pragma unroll
      for (int mi = 0; mi < 4; ++mi) {
        int r0 = mi * 16 + lg4;  // atom rows (4 consecutive)
        bf16x4 o;
#pragma unroll
        for (int j = 0; j < 4; ++j) {
          float x = acc[ni][mi][j] + bv;
          o[j] = (__bf16)(x >= 0.0f ? x : 0.01f * x);
        }
        *(bf16x4*)&sXT[n * 64 + (r0 ^ ((n & 7) << 3))] = o;
      }
    }
  };

  // ---- aggregation: aggT = sXT @ sAdj (sym), scale cols by rdeg -> sRow ----
  auto agg_mm = [&]() {
    f32x4 acc[2][4];
#pragma unroll
    for (int mi = 0; mi < 2; ++mi)
#pragma unroll
      for (int ni = 0; ni < 4; ++ni) acc[mi][ni] = {0.f, 0.f, 0.f, 0.f};
#pragma unroll
    for (int ks = 0; ks < 2; ++ks) {
      bf16x8 afrag[2], bfrag[4];
#pragma unroll
      for (int mi = 0; mi < 2; ++mi) {
        int m = (2 * w + mi) * 16 + lr;  // feature row
        afrag[mi] = *(const bf16x8*)&sXT[m * 64 + ((ks * 32 + k0) ^ ((m & 7) << 3))];
      }
#pragma unroll
      for (int ni = 0; ni < 4; ++ni) {
        int n = ni * 16 + lr;  // atom column
        bfrag[ni] = *(const bf16x8*)&sAdj[n * 64 + ((ks * 32 + k0) ^ ((n & 7) << 3))];
      }
#pragma unroll
      for (int mi = 0; mi < 2; ++mi)
#pragma unroll
        for (int ni = 0; ni < 4; ++ni)
          acc[mi][ni] = __builtin_amdgcn_mfma_f32_16x16x32_bf16(
              afrag[mi], bfrag[ni], acc[mi][ni], 0, 0, 0);
    }
#pragma unroll
    for (int ni = 0; ni < 4; ++ni) {
      int a = ni * 16 + lr;  // atom column
      float rv = sRdg[a];
#pragma unroll
      for (int mi = 0; mi < 2; ++mi) {
        int f0r = (2 * w + mi) * 16 + lg4;  // feature rows (4 consecutive)
        bf16x4 o;
#pragma unroll
        for (int j = 0; j < 4; ++j) o[j] = (__bf16)(acc[mi][ni][j] * rv);
        *(bf16x4*)&sRow[a * 128 + (f0r ^ ((a & 7) << 3))] = o;
      }
    }
  };

  conv_mm(WtI, b_init);  // x1 = lrelu(node @ W_init + b_init) -> sXT
  __syncthreads();

  for (int l = 0; l < NCONV; ++l) {
    agg_mm();  // sRow = agg
    __syncthreads();
    conv_mm(WtC + l * FDIM * FDIM, b_conv + l * FDIM);  // sXT = lrelu(agg@W+b)
    __syncthreads();
  }

  // ---- mean pool over atoms ----
  if (t < FDIM) {
    float s = 0.0f;
#pragma unroll
    for (int g = 0; g < 8; ++g) {
      bf16x8 v = *(const bf16x8*)&sXT[t * 64 + ((g * 8) ^ ((t & 7) << 3))];
#pragma unroll
      for (int i = 0; i < 8; ++i) s += (float)v[i];
    }
    g_out[(size_t)b * FDIM + t] = s * (1.0f / 64.0f);
  }
}

// ---------------- kernel 2: FC head, 16 molecules per block ----------------
__launch_bounds__(256, 2)
__global__ void head_fc(const float* __restrict__ g,
                        const float* __restrict__ W_fc0, const float* __restrict__ b_fc0,
                        const float* __restrict__ W_fc1, const float* __restrict__ b_fc1,
                        const float* __restrict__ W_out, const float* __restrict__ b_out,
                        float* __restrict__ out) {
  __shared__ __align__(16) float sG[16 * FDIM];   // 8 KB
  __shared__ float sH[16 * (HDIM + 1)];           // 16.06 KB
  __shared__ float sRed[4 * 16];

  const int t = threadIdx.x;
  const int lane = t & 63;
  const int w = t >> 6;
  const int r0 = blockIdx.x * 16;

  {
    const float4* gs = (const float4*)(g + (size_t)r0 * FDIM);
    float4* gd = (float4*)sG;
#pragma unroll
    for (int u = 0; u < 2; ++u) gd[t + 256 * u] = gs[t + 256 * u];
  }
  __syncthreads();

  // h0[r][t] = lrelu(sum_k g[r][k] * W_fc0[k][t] + b_fc0[t])
  float acc[16];
  {
    float bv = b_fc0[t];
#pragma unroll
    for (int r = 0; r < 16; ++r) acc[r] = bv;
    for (int k = 0; k < FDIM; ++k) {
      float wv = W_fc0[k * HDIM + t];
#pragma unroll
      for (int r = 0; r < 16; ++r) acc[r] += sG[r * FDIM + k] * wv;
    }
#pragma unroll
    for (int r = 0; r < 16; ++r) sH[r * (HDIM + 1) + t] = lrelu(acc[r]);
  }
  __syncthreads();

  // h1 + W_out
  {
    float bv = b_fc1[t];
#pragma unroll
    for (int r = 0; r < 16; ++r) acc[r] = bv;
    for (int k = 0; k < HDIM; ++k) {
      float wv = W_fc1[k * HDIM + t];
#pragma unroll
      for (int r = 0; r < 16; ++r) acc[r] += sH[r * (HDIM + 1) + k] * wv;
    }
    float wo = W_out[t];
#pragma unroll
    for (int r = 0; r < 16; ++r) acc[r] = lrelu(acc[r]) * wo;
  }
#pragma unroll
  for (int r = 0; r < 16; ++r) {
    float v = acc[r];
    v += __shfl_down(v, 32); v += __shfl_down(v, 16); v += __shfl_down(v, 8);
    v += __shfl_down(v, 4);  v += __shfl_down(v, 2);  v += __shfl_down(v, 1);
    if (lane == 0) sRed[w * 16 + r] = v;
  }
  __syncthreads();
  if (t < 16)
    out[r0 + t] = sRed[t] + sRed[16 + t] + sRed[32 + t] + sRed[48 + t] + b_out[0];
}

extern "C" void kernel_launch(void* const* d_in, const int* in_sizes, int n_in,
                              void* d_out, int out_size, void* d_ws, size_t ws_size,
                              hipStream_t stream) {
  (void)in_sizes; (void)n_in; (void)ws_size; (void)out_size;
  const float* node   = (const float*)d_in[0];
  const float* adj    = (const float*)d_in[1];
  const float* W_init = (const float*)d_in[2];
  const float* b_init = (const float*)d_in[3];
  const float* W_conv = (const float*)d_in[4];
  const float* b_conv = (const float*)d_in[5];
  const float* W_fc0  = (const float*)d_in[6];
  const float* b_fc0  = (const float*)d_in[7];
  const float* W_fc1  = (const float*)d_in[8];
  const float* b_fc1  = (const float*)d_in[9];
  const float* W_out  = (const float*)d_in[10];
  const float* b_out  = (const float*)d_in[11];
  float* out = (float*)d_out;

  // ws layout: WtI bf16[16384] | WtC bf16[65536] | g f32[4096*128]
  __bf16* WtI = (__bf16*)d_ws;
  __bf16* WtC = WtI + FDIM * FDIM;
  float* g = (float*)((char*)d_ws + 160 * 1024);

  prep_weights<<<320, 256, 0, stream>>>(W_init, W_conv, WtI, WtC);
  gcn_mfma<<<4096, 256, 0, stream>>>(node, adj, WtI, WtC, b_init, b_conv, g);
  head_fc<<<256, 256, 0, stream>>>(g, W_fc0, b_fc0, W_fc1, b_fc1, W_out, b_out, out);
}

// Round 3
// 142.184 us; speedup vs baseline: 5.7563x; 1.3338x over previous
//
#include <hip/hip_runtime.h>

#define NATOMS 64
#define VDIM 100
#define FDIM 128
#define HDIM 256
#define NCONV 4

typedef __bf16 bf16x8 __attribute__((ext_vector_type(8)));
typedef __bf16 bf16x4 __attribute__((ext_vector_type(4)));
typedef float f32x4 __attribute__((ext_vector_type(4)));

__device__ __forceinline__ float lrelu(float x) {
  return x >= 0.0f ? x : 0.01f * x;
}

// ---------------- kernel 0: pack weights into per-fragment order ----------------
// Layout: [n16 tile 0..7][ks 0..3][lane 0..63][e 0..7] bf16, where for lane
// (g=lane>>4, lr=lane&15): element = W[k][n], n = n16*16+lr, k = ks*32+g*8+e.
// A wave's B-fragment load is then one contiguous 1 KB read.
__global__ void prep_weights(const float* __restrict__ Wi,
                             const float* __restrict__ Wc,
                             __bf16* __restrict__ WtI,
                             __bf16* __restrict__ WtC) {
  int idx = blockIdx.x * 256 + threadIdx.x;  // 81920 total
  int e = idx & 7;
  int lane = (idx >> 3) & 63;
  int ks = (idx >> 9) & 3;
  int n16 = (idx >> 11) & 7;
  int l = idx >> 14;  // 0 = init, 1..4 = conv layers
  int n = n16 * 16 + (lane & 15);
  int k = ks * 32 + (lane >> 4) * 8 + e;
  if (l == 0) {
    WtI[idx] = (__bf16)(k < VDIM ? Wi[k * FDIM + n] : 0.0f);
  } else {
    WtC[(l - 1) * 16384 + (idx & 16383)] =
        (__bf16)Wc[(l - 1) * FDIM * FDIM + k * FDIM + n];
  }
}

// conv matmul: acc = sRow @ W ; epilogue either produces agg A-frags in-register
// (cross-lane relayout via shfl) or pools (final layer).
template <bool PRODUCE_FRAG>
__device__ __forceinline__ void conv_step(
    const __bf16* __restrict__ Wt, const float* __restrict__ bias,
    const __bf16* __restrict__ sRow, bf16x8 xfrag[2][2], float psum[2],
    const int w, const int lane) {
  const int lr = lane & 15;
  const int g = lane >> 4;
  const int k0 = g * 8;
  f32x4 acc[2][4];
#pragma unroll
  for (int ni = 0; ni < 2; ++ni)
#pragma unroll
    for (int mi = 0; mi < 4; ++mi) acc[ni][mi] = {0.f, 0.f, 0.f, 0.f};
#pragma unroll
  for (int ks = 0; ks < 4; ++ks) {
    bf16x8 bfrag[2], afrag[4];
#pragma unroll
    for (int ni = 0; ni < 2; ++ni)
      bfrag[ni] = *(const bf16x8*)&Wt[(((2 * w + ni) * 4 + ks) * 64 + lane) * 8];
#pragma unroll
    for (int mi = 0; mi < 4; ++mi) {
      int m = mi * 16 + lr;
      afrag[mi] = *(const bf16x8*)&sRow[m * 128 + ((ks * 32 + k0) ^ ((m & 7) << 3))];
    }
#pragma unroll
    for (int ni = 0; ni < 2; ++ni)
#pragma unroll
      for (int mi = 0; mi < 4; ++mi)
        acc[ni][mi] = __builtin_amdgcn_mfma_f32_16x16x32_bf16(
            afrag[mi], bfrag[ni], acc[ni][mi], 0, 0, 0);
  }
#pragma unroll
  for (int ni = 0; ni < 2; ++ni) {
    float bv = bias[(2 * w + ni) * 16 + lr];
    if constexpr (PRODUCE_FRAG) {
      // D-frag (1 feature col x 4 atom rows) -> bf16 dword pairs
      uint2 d[4];
#pragma unroll
      for (int mi = 0; mi < 4; ++mi) {
        bf16x4 o;
#pragma unroll
        for (int j = 0; j < 4; ++j) o[j] = (__bf16)lrelu(acc[ni][mi][j] + bv);
        d[mi] = __builtin_bit_cast(uint2, o);
      }
      // relayout to agg A-frag: lane(g,lr) dword q of xfrag[ni][ksp] = atoms
      // ksp*32+8g+2q+{0,1} of feature (2w+ni)*16+lr, sourced from
      // lane (2(g&1)+(q>>1))*16+lr, register d[2ksp+(g>>1)], half (q&1).
#pragma unroll
      for (int ksp = 0; ksp < 2; ++ksp) {
        unsigned r[4];
#pragma unroll
        for (int q = 0; q < 4; ++q) {
          int src = (2 * (g & 1) + (q >> 1)) * 16 + lr;
          unsigned lo = (q & 1) ? d[2 * ksp].y : d[2 * ksp].x;
          unsigned hi = (q & 1) ? d[2 * ksp + 1].y : d[2 * ksp + 1].x;
          unsigned va = (unsigned)__shfl((int)lo, src);
          unsigned vb = (unsigned)__shfl((int)hi, src);
          r[q] = (g >> 1) ? vb : va;
        }
        xfrag[ni][ksp] =
            __builtin_bit_cast(bf16x8, make_uint4(r[0], r[1], r[2], r[3]));
      }
    } else {
      float s = 0.f;
#pragma unroll
      for (int mi = 0; mi < 4; ++mi)
#pragma unroll
        for (int j = 0; j < 4; ++j) s += lrelu(acc[ni][mi][j] + bv);
      psum[ni] = s;  // sum over this lane's 16 atoms of feature (2w+ni)*16+lr
    }
  }
}

// aggregation: aggT = xT @ A (A symmetric 0/1), scale atom-columns by rdg -> sRow
__device__ __forceinline__ void agg_step(const __bf16* __restrict__ sAdj,
                                         const bf16x8 xfrag[2][2],
                                         __bf16* __restrict__ sRow,
                                         const float rdgv[4], const int w,
                                         const int lane) {
  const int lr = lane & 15;
  const int g = lane >> 4;
  const int k0 = g * 8;
  f32x4 acc[2][4];
#pragma unroll
  for (int mi = 0; mi < 2; ++mi)
#pragma unroll
    for (int ni = 0; ni < 4; ++ni) acc[mi][ni] = {0.f, 0.f, 0.f, 0.f};
#pragma unroll
  for (int ks = 0; ks < 2; ++ks) {
    bf16x8 bfrag[4];
#pragma unroll
    for (int ni = 0; ni < 4; ++ni) {
      int n = ni * 16 + lr;
      bfrag[ni] = *(const bf16x8*)&sAdj[n * 64 + ((ks * 32 + k0) ^ ((n & 7) << 3))];
    }
#pragma unroll
    for (int mi = 0; mi < 2; ++mi)
#pragma unroll
      for (int ni = 0; ni < 4; ++ni)
        acc[mi][ni] = __builtin_amdgcn_mfma_f32_16x16x32_bf16(
            xfrag[mi][ks], bfrag[ni], acc[mi][ni], 0, 0, 0);
  }
#pragma unroll
  for (int ni = 0; ni < 4; ++ni) {
    float rv = rdgv[ni];
    int a = ni * 16 + lr;
#pragma unroll
    for (int mi = 0; mi < 2; ++mi) {
      int f0r = (2 * w + mi) * 16 + g * 4;
      bf16x4 o;
#pragma unroll
      for (int j = 0; j < 4; ++j) o[j] = (__bf16)(acc[mi][ni][j] * rv);
      *(bf16x4*)&sRow[a * 128 + (f0r ^ ((a & 7) << 3))] = o;
    }
  }
}

// ---------------- kernel 1: fused GCN, one molecule per block ----------------
__launch_bounds__(256, 4)
__global__ void gcn_mfma(const float* __restrict__ node,
                         const float* __restrict__ adj,
                         const __bf16* __restrict__ WtI,
                         const __bf16* __restrict__ WtC,
                         const float* __restrict__ b_init,
                         const float* __restrict__ b_conv,
                         float* __restrict__ g_out) {
  __shared__ __align__(16) __bf16 sRow[NATOMS * FDIM];   // 16 KB
  __shared__ __align__(16) __bf16 sAdj[NATOMS * NATOMS]; // 8 KB
  __shared__ float sRdg[NATOMS];                         // 256 B

  const int b = blockIdx.x;
  const int t = threadIdx.x;
  const int lane = t & 63;
  const int w = t >> 6;

  // ---- stage adjacency (bf16 0/1, swizzled) + shuffle-reduced degrees ----
  {
    const float* adjB = adj + (size_t)b * NATOMS * NATOMS;
#pragma unroll
    for (int half = 0; half < 2; ++half) {
      int n = (t >> 3) + half * 32;
      int gi = t & 7;
      float4 a0 = *(const float4*)&adjB[n * 64 + gi * 8];
      float4 a1 = *(const float4*)&adjB[n * 64 + gi * 8 + 4];
      bf16x8 v;
      v[0] = (__bf16)a0.x; v[1] = (__bf16)a0.y; v[2] = (__bf16)a0.z; v[3] = (__bf16)a0.w;
      v[4] = (__bf16)a1.x; v[5] = (__bf16)a1.y; v[6] = (__bf16)a1.z; v[7] = (__bf16)a1.w;
      *(bf16x8*)&sAdj[n * 64 + ((gi * 8) ^ ((n & 7) << 3))] = v;
      float p = a0.x + a0.y + a0.z + a0.w + a1.x + a1.y + a1.z + a1.w;
      p += __shfl_xor(p, 1); p += __shfl_xor(p, 2); p += __shfl_xor(p, 4);
      if (gi == 0) sRdg[n] = 1.0f / fmaxf(p, 1.0f);
    }
  }
  // ---- stage node -> sRow [atom][128] bf16, zero-pad k>=100, swizzled ----
  {
    const float* nodeB = node + (size_t)b * NATOMS * VDIM;
#pragma unroll
    for (int u0 = 0; u0 < 4; ++u0) {
      int u = t + 256 * u0;
      int n = u >> 4, gi = u & 15, kk = gi * 8;
      bf16x8 v;
      if (kk + 8 <= VDIM) {
        float4 a0 = *(const float4*)&nodeB[n * VDIM + kk];
        float4 a1 = *(const float4*)&nodeB[n * VDIM + kk + 4];
        v[0] = (__bf16)a0.x; v[1] = (__bf16)a0.y; v[2] = (__bf16)a0.z; v[3] = (__bf16)a0.w;
        v[4] = (__bf16)a1.x; v[5] = (__bf16)a1.y; v[6] = (__bf16)a1.z; v[7] = (__bf16)a1.w;
      } else {
#pragma unroll
        for (int i = 0; i < 8; ++i)
          v[i] = (__bf16)((kk + i < VDIM) ? nodeB[n * VDIM + kk + i] : 0.0f);
      }
      *(bf16x8*)&sRow[n * 128 + (kk ^ ((n & 7) << 3))] = v;
    }
  }
  __syncthreads();

  float rdgv[4];
#pragma unroll
  for (int ni = 0; ni < 4; ++ni) rdgv[ni] = sRdg[ni * 16 + (lane & 15)];

  bf16x8 xfrag[2][2];
  float psum[2];

  conv_step<true>(WtI, b_init, sRow, xfrag, psum, w, lane);
  __syncthreads();

#pragma unroll
  for (int l = 0; l < NCONV; ++l) {
    agg_step(sAdj, xfrag, sRow, rdgv, w, lane);
    __syncthreads();
    if (l < NCONV - 1) {
      conv_step<true>(WtC + l * 16384, b_conv + l * FDIM, sRow, xfrag, psum, w, lane);
      __syncthreads();
    } else {
      conv_step<false>(WtC + l * 16384, b_conv + l * FDIM, sRow, xfrag, psum, w, lane);
    }
  }

  // ---- mean pool: reduce psum over the 4 lane-groups, write 32 feats/wave ----
#pragma unroll
  for (int ni = 0; ni < 2; ++ni) {
    float s = psum[ni];
    s += __shfl_xor(s, 16);
    s += __shfl_xor(s, 32);
    if (lane < 16)
      g_out[(size_t)b * FDIM + (2 * w + ni) * 16 + lane] = s * (1.0f / 64.0f);
  }
}

// ---------------- kernel 2: FC head, 16 molecules per block ----------------
__launch_bounds__(256, 2)
__global__ void head_fc(const float* __restrict__ g,
                        const float* __restrict__ W_fc0, const float* __restrict__ b_fc0,
                        const float* __restrict__ W_fc1, const float* __restrict__ b_fc1,
                        const float* __restrict__ W_out, const float* __restrict__ b_out,
                        float* __restrict__ out) {
  __shared__ __align__(16) float sG[16 * FDIM];
  __shared__ float sH[16 * (HDIM + 1)];
  __shared__ float sRed[4 * 16];

  const int t = threadIdx.x;
  const int lane = t & 63;
  const int w = t >> 6;
  const int r0 = blockIdx.x * 16;

  {
    const float4* gs = (const float4*)(g + (size_t)r0 * FDIM);
    float4* gd = (float4*)sG;
#pragma unroll
    for (int u = 0; u < 2; ++u) gd[t + 256 * u] = gs[t + 256 * u];
  }
  __syncthreads();

  float acc[16];
  {
    float bv = b_fc0[t];
#pragma unroll
    for (int r = 0; r < 16; ++r) acc[r] = bv;
    for (int k = 0; k < FDIM; ++k) {
      float wv = W_fc0[k * HDIM + t];
#pragma unroll
      for (int r = 0; r < 16; ++r) acc[r] += sG[r * FDIM + k] * wv;
    }
#pragma unroll
    for (int r = 0; r < 16; ++r) sH[r * (HDIM + 1) + t] = lrelu(acc[r]);
  }
  __syncthreads();

  {
    float bv = b_fc1[t];
#pragma unroll
    for (int r = 0; r < 16; ++r) acc[r] = bv;
    for (int k = 0; k < HDIM; ++k) {
      float wv = W_fc1[k * HDIM + t];
#pragma unroll
      for (int r = 0; r < 16; ++r) acc[r] += sH[r * (HDIM + 1) + k] * wv;
    }
    float wo = W_out[t];
#pragma unroll
    for (int r = 0; r < 16; ++r) acc[r] = lrelu(acc[r]) * wo;
  }
#pragma unroll
  for (int r = 0; r < 16; ++r) {
    float v = acc[r];
    v += __shfl_down(v, 32); v += __shfl_down(v, 16); v += __shfl_down(v, 8);
    v += __shfl_down(v, 4);  v += __shfl_down(v, 2);  v += __shfl_down(v, 1);
    if (lane == 0) sRed[w * 16 + r] = v;
  }
  __syncthreads();
  if (t < 16)
    out[r0 + t] = sRed[t] + sRed[16 + t] + sRed[32 + t] + sRed[48 + t] + b_out[0];
}

extern "C" void kernel_launch(void* const* d_in, const int* in_sizes, int n_in,
                              void* d_out, int out_size, void* d_ws, size_t ws_size,
                              hipStream_t stream) {
  (void)in_sizes; (void)n_in; (void)ws_size; (void)out_size;
  const float* node   = (const float*)d_in[0];
  const float* adj    = (const float*)d_in[1];
  const float* W_init = (const float*)d_in[2];
  const float* b_init = (const float*)d_in[3];
  const float* W_conv = (const float*)d_in[4];
  const float* b_conv = (const float*)d_in[5];
  const float* W_fc0  = (const float*)d_in[6];
  const float* b_fc0  = (const float*)d_in[7];
  const float* W_fc1  = (const float*)d_in[8];
  const float* b_fc1  = (const float*)d_in[9];
  const float* W_out  = (const float*)d_in[10];
  const float* b_out  = (const float*)d_in[11];
  float* out = (float*)d_out;

  // ws layout: WtI bf16[16384] | WtC bf16[65536] | g f32[4096*128]
  __bf16* WtI = (__bf16*)d_ws;
  __bf16* WtC = WtI + 16384;
  float* g = (float*)((char*)d_ws + 160 * 1024);

  prep_weights<<<320, 256, 0, stream>>>(W_init, W_conv, WtI, WtC);
  gcn_mfma<<<4096, 256, 0, stream>>>(node, adj, WtI, WtC, b_init, b_conv, g);
  head_fc<<<256, 256, 0, stream>>>(g, W_fc0, b_fc0, W_fc1, b_fc1, W_out, b_out, out);
}